// Round 2
// baseline (3617.970 us; speedup 1.0000x reference)
//
#include <hip/hip_runtime.h>
#include <hip/hip_cooperative_groups.h>
#include <math.h>

namespace cg = cooperative_groups;

#define N_NODES 150000
#define NODE_STRIDE 150016   // padded per-step stride for meta array
#define DIM 100
#define D4 25                // DIM/4 float4 chunks
#define T_STEPS 16
#define E_EDGES 262144
#define S_SEEDS 4096
#define K_CAND 9
#define SPB 16               // seeds per LSTM block (fallback path)
#define SPBC 8               // seeds per LSTM group (coop path: 512 groups)
#define NPB 8                // nodes per fused_agg block (fallback path)
#define NPBC 16              // node-groups per 512-thread coop block

#define CB 64                // coarse buckets per step
#define BSPAN 2344           // nodes per coarse bucket; 64*2344 = 150016 >= N
#define EPT 8                // edges per thread in coarse passes
#define EPB (256 * EPT)      // 2048 edges per coarse block
#define CBLK (E_EDGES / EPB) // 128 coarse blocks per step

__device__ __forceinline__ float sigmoidf_(float x) {
    return 1.0f / (1.0f + __expf(-x));
}

// ============ CSR build: atomic-free two-level counting sort ============

__global__ __launch_bounds__(256) void coarse_hist(
    const int* __restrict__ dst, int* __restrict__ bh) {
    int t = blockIdx.x / CBLK;
    int blk = blockIdx.x % CBLK;
    int base = t * E_EDGES + blk * EPB;
    int tid = threadIdx.x;
    __shared__ int h[CB];
    if (tid < CB) h[tid] = 0;
    __syncthreads();
#pragma unroll
    for (int e = 0; e < EPT; e++) {
        int d = dst[base + e * 256 + tid];
        atomicAdd(&h[d / BSPAN], 1);
    }
    __syncthreads();
    if (tid < CB) bh[(t * CBLK + blk) * CB + tid] = h[tid];
}

__global__ __launch_bounds__(64) void scan_bh(
    int* __restrict__ bh, int* __restrict__ coffs) {
    int t = blockIdx.x;
    int b = threadIdx.x;          // 64 threads = 64 buckets
    int run = 0;
    for (int blk = 0; blk < CBLK; blk++) {
        int idx = (t * CBLK + blk) * CB + b;
        int v = bh[idx];
        bh[idx] = run;
        run += v;
    }
    __shared__ int tot[CB];
    tot[b] = run;
    __syncthreads();
    if (b == 0) {
        int r = 0;
        for (int i = 0; i < CB; i++) { int c = tot[i]; tot[i] = r; r += c; }
    }
    __syncthreads();
    coffs[t * (CB + 1) + b] = tot[b];
    if (b == 0) coffs[t * (CB + 1) + CB] = E_EDGES;
}

__global__ __launch_bounds__(256) void coarse_scatter(
    const int* __restrict__ src, const int* __restrict__ dst,
    const int* __restrict__ cat, const int* __restrict__ bh,
    const int* __restrict__ coffs, int2* __restrict__ cbuf) {
    int t = blockIdx.x / CBLK;
    int blk = blockIdx.x % CBLK;
    int base = t * E_EDGES + blk * EPB;
    int tid = threadIdx.x;
    __shared__ int h[CB];
    __shared__ int gbase[CB];
    if (tid < CB) h[tid] = 0;
    __syncthreads();
    int rank[EPT], bb[EPT], dd[EPT];
#pragma unroll
    for (int e = 0; e < EPT; e++) {
        int d = dst[base + e * 256 + tid];
        int b = d / BSPAN;
        dd[e] = d; bb[e] = b;
        rank[e] = atomicAdd(&h[b], 1);
    }
    __syncthreads();
    if (tid < CB)
        gbase[tid] = coffs[t * (CB + 1) + tid] + bh[(t * CBLK + blk) * CB + tid];
    __syncthreads();
#pragma unroll
    for (int e = 0; e < EPT; e++) {
        int i = base + e * 256 + tid;
        int2 en;
        en.x = src[i] | (cat[i] << 18);
        en.y = dd[e];
        cbuf[(size_t)t * E_EDGES + gbase[bb[e]] + rank[e]] = en;
    }
}

__global__ __launch_bounds__(256) void fine_build(
    const int2* __restrict__ cbuf, const int* __restrict__ coffs,
    int4* __restrict__ meta, int* __restrict__ sorted) {
    int t = blockIdx.x >> 6;
    int b = blockIdx.x & 63;
    int node0 = b * BSPAN;
    int nodes = min(BSPAN, N_NODES - node0);
    int ebeg = coffs[t * (CB + 1) + b];
    int eend = coffs[t * (CB + 1) + b + 1];
    const int2* ebuf = cbuf + (size_t)t * E_EDGES;
    int4* mt = meta + (size_t)t * NODE_STRIDE;
    int* srt = sorted + (size_t)t * E_EDGES;
    __shared__ int cnt[BSPAN];
    __shared__ int begs[BSPAN];
    __shared__ int sums[256];
    int tid = threadIdx.x;

    for (int j = tid; j < BSPAN; j += 256) cnt[j] = 0;
    __syncthreads();
    for (int e = ebeg + tid; e < eend; e += 256)
        atomicAdd(&cnt[ebuf[e].y - node0], 1);
    __syncthreads();

    const int chunk = (BSPAN + 255) / 256;   // 10
    int cbeg = tid * chunk;
    int cend = min(cbeg + chunk, BSPAN);
    int s = 0;
    for (int j = cbeg; j < cend; j++) s += cnt[j];
    sums[tid] = s;
    __syncthreads();
    for (int d = 1; d < 256; d <<= 1) {
        int v = (tid >= d) ? sums[tid - d] : 0;
        __syncthreads();
        sums[tid] += v;
        __syncthreads();
    }
    int run = (tid == 0) ? 0 : sums[tid - 1];
    for (int j = cbeg; j < cend; j++) {
        int c = cnt[j];
        begs[j] = run;
        cnt[j] = run;                // cursor
        run += c;
    }
    __syncthreads();

    for (int e = ebeg + tid; e < eend; e += 256) {
        int2 en = ebuf[e];
        int pos = atomicAdd(&cnt[en.y - node0], 1);
        srt[ebeg + pos] = en.x;
    }
    __syncthreads();

    for (int j = tid; j < nodes; j += 256) {
        int lbeg = begs[j];
        int deg = cnt[j] - lbeg;
        int gbeg = ebeg + lbeg;
        int4 m;
        m.x = gbeg | (deg << 19);
        m.y = (deg > 0) ? srt[gbeg] : 0;
        m.z = (deg > 1) ? srt[gbeg + 1] : 0;
        m.w = (deg > 2) ? srt[gbeg + 2] : 0;
        mt[node0 + j] = m;
    }
}

// ============ Shared phase bodies (used by coop kernel AND fallback) ========

__device__ __forceinline__ void agg_node(
    const float* __restrict__ emb_in, float* __restrict__ emb_out,
    const float* __restrict__ rel_emb, const int4* __restrict__ mt,
    const int* __restrict__ srt, int node, int lane) {
    bool act = lane < D4;
    float4 own = act ? ((const float4*)(emb_in + (size_t)node * DIM))[lane]
                     : make_float4(0.f, 0.f, 0.f, 0.f);
    int4 m = mt[node];
    int deg = ((unsigned)m.x) >> 19;
    int beg = m.x & 0x7FFFF;
    float4 acc = make_float4(0.f, 0.f, 0.f, 0.f);
    if (act) {
        if (deg > 0) {
            float4 mm = ((const float4*)(emb_in + (size_t)(m.y & 0x3FFFF) * DIM))[lane];
            float4 rr = ((const float4*)(rel_emb + (size_t)(m.y >> 18) * DIM))[lane];
            acc.x += mm.x * rr.x; acc.y += mm.y * rr.y;
            acc.z += mm.z * rr.z; acc.w += mm.w * rr.w;
        }
        if (deg > 1) {
            float4 mm = ((const float4*)(emb_in + (size_t)(m.z & 0x3FFFF) * DIM))[lane];
            float4 rr = ((const float4*)(rel_emb + (size_t)(m.z >> 18) * DIM))[lane];
            acc.x += mm.x * rr.x; acc.y += mm.y * rr.y;
            acc.z += mm.z * rr.z; acc.w += mm.w * rr.w;
        }
        if (deg > 2) {
            float4 mm = ((const float4*)(emb_in + (size_t)(m.w & 0x3FFFF) * DIM))[lane];
            float4 rr = ((const float4*)(rel_emb + (size_t)(m.w >> 18) * DIM))[lane];
            acc.x += mm.x * rr.x; acc.y += mm.y * rr.y;
            acc.z += mm.z * rr.z; acc.w += mm.w * rr.w;
        }
    }
    for (int e = beg + 3; e < beg + deg; e++) {
        int p = srt[e];
        if (act) {
            float4 mm = ((const float4*)(emb_in + (size_t)(p & 0x3FFFF) * DIM))[lane];
            float4 rr = ((const float4*)(rel_emb + (size_t)(p >> 18) * DIM))[lane];
            acc.x += mm.x * rr.x; acc.y += mm.y * rr.y;
            acc.z += mm.z * rr.z; acc.w += mm.w * rr.w;
        }
    }
    if (act) {
        float inv = (deg > 0) ? 1.0f / (float)deg : 0.0f;
        own.x += acc.x * inv; own.y += acc.y * inv;
        own.z += acc.z * inv; own.w += acc.w * inv;
        ((float4*)(emb_out + (size_t)node * DIM))[lane] = own;
    }
}

// ============ Persistent cooperative 16-step kernel =========================
__global__ __launch_bounds__(512) void time_loop(
    const float* __restrict__ node_emb, float* __restrict__ emb_a,
    float* __restrict__ emb_b, float* __restrict__ cst,
    const float* __restrict__ rel_emb,
    const int4* __restrict__ meta, const int* __restrict__ sorted,
    const int* __restrict__ seeds_all,
    const float* __restrict__ W_ih, const float* __restrict__ W_hh,
    const float* __restrict__ b_ih, const float* __restrict__ b_hh,
    float* __restrict__ seedh_all, float* __restrict__ cnew) {
    cg::grid_group grid = cg::this_grid();
    __shared__ __align__(16) float xs[SPBC][DIM];
    __shared__ __align__(16) float hs[SPBC][DIM];
    __shared__ __align__(16) float gates[SPBC][4 * DIM];

    const float* cur = node_emb;
    for (int t = 0; t < T_STEPS; t++) {
        float* nxt = (t & 1) ? emb_a : emb_b;
        const int4* mt = meta + (size_t)t * NODE_STRIDE;
        const int* srt = sorted + (size_t)t * E_EDGES;
        const int* seeds = seeds_all + (size_t)t * S_SEEDS;
        float* seedh = seedh_all + (size_t)t * S_SEEDS * DIM;

        // ---- phase A: fused aggregation + residual over all nodes ----
        {
            int g = threadIdx.x >> 5;
            int lane = threadIdx.x & 31;
            for (int node = blockIdx.x * NPBC + g; node < N_NODES;
                 node += gridDim.x * NPBC)
                agg_node(cur, nxt, rel_emb, mt, srt, node, lane);
        }
        grid.sync();

        // ---- phase B: LSTM on seeds (x from nxt, h_prev from cur) ----
        for (int grp = blockIdx.x; grp < S_SEEDS / SPBC; grp += gridDim.x) {
            int tid = threadIdx.x;
            int base = grp * SPBC;
            for (int idx = tid; idx < SPBC * D4; idx += 512) {
                int s = idx / D4, q = idx - s * D4;
                int node = seeds[base + s];
                ((float4*)xs[s])[q] =
                    ((const float4*)(nxt + (size_t)node * DIM))[q];
                ((float4*)hs[s])[q] =
                    ((const float4*)(cur + (size_t)node * DIM))[q];
            }
            __syncthreads();

            if (tid < 4 * DIM) {
                int j = tid;
                float acc[SPBC];
#pragma unroll
                for (int s = 0; s < SPBC; s++) acc[s] = 0.0f;
                const float4* wi = (const float4*)(W_ih + (size_t)j * DIM);
                const float4* wh = (const float4*)(W_hh + (size_t)j * DIM);
                for (int dc = 0; dc < D4; dc++) {
                    float4 a = wi[dc], b = wh[dc];
#pragma unroll
                    for (int s = 0; s < SPBC; s++) {
                        float4 x = ((const float4*)xs[s])[dc];
                        float4 h = ((const float4*)hs[s])[dc];
                        acc[s] += x.x * a.x + x.y * a.y + x.z * a.z + x.w * a.w
                                + h.x * b.x + h.y * b.y + h.z * b.z + h.w * b.w;
                    }
                }
                float bbv = b_ih[j] + b_hh[j];
#pragma unroll
                for (int s = 0; s < SPBC; s++) gates[s][j] = acc[s] + bbv;
            }
            __syncthreads();

            for (int idx = tid; idx < SPBC * D4; idx += 512) {
                int s = idx / D4, q = idx - s * D4;
                int node = seeds[base + s];
                float4 ig = ((const float4*)gates[s])[q];
                float4 fg = ((const float4*)(gates[s] + DIM))[q];
                float4 gg = ((const float4*)(gates[s] + 2 * DIM))[q];
                float4 og = ((const float4*)(gates[s] + 3 * DIM))[q];
                float4 cp = ((const float4*)(cst + (size_t)node * DIM))[q];
                float4 cn, hn;
                cn.x = sigmoidf_(fg.x) * cp.x + sigmoidf_(ig.x) * tanhf(gg.x);
                cn.y = sigmoidf_(fg.y) * cp.y + sigmoidf_(ig.y) * tanhf(gg.y);
                cn.z = sigmoidf_(fg.z) * cp.z + sigmoidf_(ig.z) * tanhf(gg.z);
                cn.w = sigmoidf_(fg.w) * cp.w + sigmoidf_(ig.w) * tanhf(gg.w);
                hn.x = sigmoidf_(og.x) * tanhf(cn.x);
                hn.y = sigmoidf_(og.y) * tanhf(cn.y);
                hn.z = sigmoidf_(og.z) * tanhf(cn.z);
                hn.w = sigmoidf_(og.w) * tanhf(cn.w);
                ((float4*)(seedh + (size_t)(base + s) * DIM))[q] = hn;
                ((float4*)(cnew + (size_t)(base + s) * DIM))[q] = cn;
            }
            __syncthreads();   // safe LDS reuse if a block owns >1 group
        }
        grid.sync();

        // ---- phase C: scatter seed h/c back (duplicates identical) ----
        for (int i = blockIdx.x * 512 + threadIdx.x; i < S_SEEDS * D4;
             i += gridDim.x * 512) {
            int sd = i / D4, q = i - sd * D4;
            int node = seeds[sd];
            ((float4*)(nxt + (size_t)node * DIM))[q] =
                ((const float4*)(seedh + (size_t)sd * DIM))[q];
            ((float4*)(cst + (size_t)node * DIM))[q] =
                ((const float4*)(cnew + (size_t)sd * DIM))[q];
        }
        grid.sync();

        cur = nxt;
    }
}

// ============ Fallback per-step kernels (used only if coop launch fails) ====
__global__ __launch_bounds__(256) void fused_agg(
    const float* __restrict__ emb_in, float* __restrict__ emb_out,
    const float* __restrict__ rel_emb, const int4* __restrict__ meta,
    const int* __restrict__ sorted) {
    int g = threadIdx.x >> 5;
    int lane = threadIdx.x & 31;
    int node = blockIdx.x * NPB + g;
    if (node >= N_NODES) return;
    agg_node(emb_in, emb_out, rel_emb, meta, sorted, node, lane);
}

__global__ __launch_bounds__(512) void lstm_kernel(
    const float* __restrict__ emb_new, const float* __restrict__ emb_old,
    const float* __restrict__ c_state, const int* __restrict__ seeds,
    const float* __restrict__ W_ih, const float* __restrict__ W_hh,
    const float* __restrict__ b_ih, const float* __restrict__ b_hh,
    float* __restrict__ h_out, float* __restrict__ c_out) {
    __shared__ __align__(16) float xs[SPB][DIM];
    __shared__ __align__(16) float hs[SPB][DIM];
    __shared__ float gates[SPB][4 * DIM];
    int tid = threadIdx.x;
    int base = blockIdx.x * SPB;

    for (int idx = tid; idx < SPB * DIM; idx += 512) {
        int s = idx / DIM, d = idx - s * DIM;
        int node = seeds[base + s];
        xs[s][d] = emb_new[(size_t)node * DIM + d];
        hs[s][d] = emb_old[(size_t)node * DIM + d];
    }
    __syncthreads();

    if (tid < 4 * DIM) {
        int j = tid;
        float acc[SPB];
#pragma unroll
        for (int s = 0; s < SPB; s++) acc[s] = 0.0f;
        const float4* wi = (const float4*)(W_ih + (size_t)j * DIM);
        const float4* wh = (const float4*)(W_hh + (size_t)j * DIM);
        for (int dc = 0; dc < D4; dc++) {
            float4 a = wi[dc], b = wh[dc];
#pragma unroll
            for (int s = 0; s < SPB; s++) {
                float4 x = ((const float4*)xs[s])[dc];
                float4 h = ((const float4*)hs[s])[dc];
                acc[s] += x.x * a.x + x.y * a.y + x.z * a.z + x.w * a.w
                        + h.x * b.x + h.y * b.y + h.z * b.z + h.w * b.w;
            }
        }
        float bb = b_ih[j] + b_hh[j];
#pragma unroll
        for (int s = 0; s < SPB; s++) gates[s][j] = acc[s] + bb;
    }
    __syncthreads();

    for (int idx = tid; idx < SPB * DIM; idx += 512) {
        int s = idx / DIM, d = idx - s * DIM;
        int node = seeds[base + s];
        float ig = gates[s][d];
        float fg = gates[s][DIM + d];
        float gg = gates[s][2 * DIM + d];
        float og = gates[s][3 * DIM + d];
        float cp = c_state[(size_t)node * DIM + d];
        float cn = sigmoidf_(fg) * cp + sigmoidf_(ig) * tanhf(gg);
        float hn = sigmoidf_(og) * tanhf(cn);
        h_out[(size_t)(base + s) * DIM + d] = hn;
        c_out[(size_t)(base + s) * DIM + d] = cn;
    }
}

__global__ __launch_bounds__(256) void scatter_seed(
    float* __restrict__ emb, float* __restrict__ c_state,
    const int* __restrict__ seeds,
    const float* __restrict__ h_new, const float* __restrict__ c_new) {
    int i = blockIdx.x * blockDim.x + threadIdx.x;  // over S*D4
    int sd = i / D4, q = i - sd * D4;
    int node = seeds[sd];
    ((float4*)(emb + (size_t)node * DIM))[q] =
        ((const float4*)(h_new + (size_t)sd * DIM))[q];
    ((float4*)(c_state + (size_t)node * DIM))[q] =
        ((const float4*)(c_new + (size_t)sd * DIM))[q];
}

// ============ Scoring ============
__global__ __launch_bounds__(64) void score_kernel(
    const float* __restrict__ seed_h, const float* __restrict__ emb,
    const int* __restrict__ cand_idx, float* __restrict__ out) {
    int n = blockIdx.x;
    int lane = threadIdx.x;
    float u0 = seed_h[(size_t)n * DIM + lane];
    float u1 = (lane + 64 < DIM) ? seed_h[(size_t)n * DIM + lane + 64] : 0.0f;
    for (int k = 0; k < K_CAND; k++) {
        int node = cand_idx[n * K_CAND + k];
        const float* ce = emb + (size_t)node * DIM;
        float p = u0 * ce[lane];
        if (lane + 64 < DIM) p += u1 * ce[lane + 64];
        for (int off = 32; off > 0; off >>= 1) p += __shfl_down(p, off);
        if (lane == 0) out[n * K_CAND + k] = p;
    }
}

extern "C" void kernel_launch(void* const* d_in, const int* in_sizes, int n_in,
                              void* d_out, int out_size, void* d_ws, size_t ws_size,
                              hipStream_t stream) {
    const float* node_emb = (const float*)d_in[0];
    const float* cx       = (const float*)d_in[1];
    const float* rel_emb  = (const float*)d_in[2];
    const float* W_ih     = (const float*)d_in[3];
    const float* W_hh     = (const float*)d_in[4];
    const float* b_ih     = (const float*)d_in[5];
    const float* b_hh     = (const float*)d_in[6];
    const int*   src      = (const int*)d_in[7];
    const int*   dst      = (const int*)d_in[8];
    const int*   cat      = (const int*)d_in[9];
    const int*   seeds    = (const int*)d_in[10];
    const int*   cand     = (const int*)d_in[11];
    float* out = (float*)d_out;

    char* wsb = (char*)d_ws;
    float* emb_a = (float*)wsb; wsb += sizeof(float) * (size_t)N_NODES * DIM;
    float* emb_b = (float*)wsb; wsb += sizeof(float) * (size_t)N_NODES * DIM;
    float* cst   = (float*)wsb; wsb += sizeof(float) * (size_t)N_NODES * DIM;
    float* cnew  = (float*)wsb; wsb += sizeof(float) * (size_t)S_SEEDS * DIM;
    float* seedh = (float*)wsb; wsb += sizeof(float) * (size_t)T_STEPS * S_SEEDS * DIM;
    int4* meta   = (int4*)wsb; wsb += sizeof(int4) * (size_t)T_STEPS * NODE_STRIDE;
    int* sorted  = (int*)wsb; wsb += sizeof(int) * (size_t)T_STEPS * E_EDGES;
    int* bh      = (int*)wsb; wsb += sizeof(int) * (size_t)T_STEPS * CBLK * CB;
    int* coffs   = (int*)wsb; wsb += sizeof(int) * T_STEPS * (CB + 1);
    // coarse entry buffer (33.6 MB) aliases emb_b: dead until first agg write
    int2* cbuf = (int2*)emb_b;

    // ---- CSR build for all 16 steps ----
    coarse_hist<<<T_STEPS * CBLK, 256, 0, stream>>>(dst, bh);
    scan_bh<<<T_STEPS, 64, 0, stream>>>(bh, coffs);
    coarse_scatter<<<T_STEPS * CBLK, 256, 0, stream>>>(
        src, dst, cat, bh, coffs, cbuf);
    fine_build<<<T_STEPS * CB, 256, 0, stream>>>(cbuf, coffs, meta, sorted);

    hipMemcpyAsync(cst, cx, sizeof(float) * (size_t)N_NODES * DIM,
                   hipMemcpyDeviceToDevice, stream);

    // ---- persistent cooperative 16-step loop ----
    static int grid_blocks = 0;
    if (grid_blocks == 0) {
        int occ = 0, ncu = 256;
        hipOccupancyMaxActiveBlocksPerMultiprocessor(
            &occ, (const void*)time_loop, 512, 0);
        hipDeviceProp_t prop;
        if (hipGetDeviceProperties(&prop, 0) == hipSuccess)
            ncu = prop.multiProcessorCount;
        if (occ < 1) occ = 1;
        grid_blocks = occ * ncu;
        int max_useful = (N_NODES + NPBC - 1) / NPBC;   // 9375
        if (grid_blocks > max_useful) grid_blocks = max_useful;
    }

    void* args[] = {
        (void*)&node_emb, (void*)&emb_a, (void*)&emb_b, (void*)&cst,
        (void*)&rel_emb, (void*)&meta, (void*)&sorted, (void*)&seeds,
        (void*)&W_ih, (void*)&W_hh, (void*)&b_ih, (void*)&b_hh,
        (void*)&seedh, (void*)&cnew
    };
    hipError_t cerr = hipLaunchCooperativeKernel(
        (const void*)time_loop, dim3(grid_blocks), dim3(512), args, 0, stream);

    if (cerr != hipSuccess) {
        // fallback: original 3-kernel-per-step loop (identical numerics,
        // proven 1543 us baseline)
        const float* cur = node_emb;
        float* bufs[2] = {emb_b, emb_a};
        for (int t = 0; t < T_STEPS; t++) {
            float* nxt = bufs[t & 1];
            fused_agg<<<(N_NODES + NPB - 1) / NPB, 256, 0, stream>>>(
                cur, nxt, rel_emb,
                meta + (size_t)t * NODE_STRIDE, sorted + (size_t)t * E_EDGES);
            lstm_kernel<<<S_SEEDS / SPB, 512, 0, stream>>>(
                nxt, cur, cst, seeds + (size_t)t * S_SEEDS,
                W_ih, W_hh, b_ih, b_hh,
                seedh + (size_t)t * S_SEEDS * DIM, cnew);
            scatter_seed<<<(S_SEEDS * D4) / 256, 256, 0, stream>>>(
                nxt, cst, seeds + (size_t)t * S_SEEDS,
                seedh + (size_t)t * S_SEEDS * DIM, cnew);
            cur = nxt;
        }
    }

    // T_STEPS even -> final buffer is emb_a on both paths
    score_kernel<<<T_STEPS * S_SEEDS, 64, 0, stream>>>(seedh, emb_a, cand, out);
}

// Round 3
// 1501.256 us; speedup vs baseline: 2.4100x; 2.4100x over previous
//
#include <hip/hip_runtime.h>
#include <math.h>

#define N_NODES 150000
#define NODE_STRIDE 150016   // padded per-step stride for meta array
#define DIM 100
#define D4 25                // DIM/4 float4 chunks
#define T_STEPS 16
#define E_EDGES 262144
#define S_SEEDS 4096
#define K_CAND 9
#define SPB 16               // seeds per LSTM block
#define NPB 8                // nodes per fused_agg block (8 groups x 32 lanes)

#define CB 64                // coarse buckets per step
#define BSPAN 2344           // nodes per coarse bucket; 64*2344 = 150016 >= N
#define EPT 8                // edges per thread in coarse passes
#define EPB (256 * EPT)      // 2048 edges per coarse block
#define CBLK (E_EDGES / EPB) // 128 coarse blocks per step

__device__ __forceinline__ float sigmoidf_(float x) {
    return 1.0f / (1.0f + __expf(-x));
}

// ============ CSR build: atomic-free two-level counting sort ============

__global__ __launch_bounds__(256) void coarse_hist(
    const int* __restrict__ dst, int* __restrict__ bh) {
    int t = blockIdx.x / CBLK;
    int blk = blockIdx.x % CBLK;
    int base = t * E_EDGES + blk * EPB;
    int tid = threadIdx.x;
    __shared__ int h[CB];
    if (tid < CB) h[tid] = 0;
    __syncthreads();
#pragma unroll
    for (int e = 0; e < EPT; e++) {
        int d = dst[base + e * 256 + tid];
        atomicAdd(&h[d / BSPAN], 1);
    }
    __syncthreads();
    if (tid < CB) bh[(t * CBLK + blk) * CB + tid] = h[tid];
}

__global__ __launch_bounds__(64) void scan_bh(
    int* __restrict__ bh, int* __restrict__ coffs) {
    int t = blockIdx.x;
    int b = threadIdx.x;          // 64 threads = 64 buckets
    int run = 0;
    for (int blk = 0; blk < CBLK; blk++) {
        int idx = (t * CBLK + blk) * CB + b;
        int v = bh[idx];
        bh[idx] = run;
        run += v;
    }
    __shared__ int tot[CB];
    tot[b] = run;
    __syncthreads();
    if (b == 0) {
        int r = 0;
        for (int i = 0; i < CB; i++) { int c = tot[i]; tot[i] = r; r += c; }
    }
    __syncthreads();
    coffs[t * (CB + 1) + b] = tot[b];
    if (b == 0) coffs[t * (CB + 1) + CB] = E_EDGES;
}

__global__ __launch_bounds__(256) void coarse_scatter(
    const int* __restrict__ src, const int* __restrict__ dst,
    const int* __restrict__ cat, const int* __restrict__ bh,
    const int* __restrict__ coffs, int2* __restrict__ cbuf) {
    int t = blockIdx.x / CBLK;
    int blk = blockIdx.x % CBLK;
    int base = t * E_EDGES + blk * EPB;
    int tid = threadIdx.x;
    __shared__ int h[CB];
    __shared__ int gbase[CB];
    if (tid < CB) h[tid] = 0;
    __syncthreads();
    int rank[EPT], bb[EPT], dd[EPT];
#pragma unroll
    for (int e = 0; e < EPT; e++) {
        int d = dst[base + e * 256 + tid];
        int b = d / BSPAN;
        dd[e] = d; bb[e] = b;
        rank[e] = atomicAdd(&h[b], 1);
    }
    __syncthreads();
    if (tid < CB)
        gbase[tid] = coffs[t * (CB + 1) + tid] + bh[(t * CBLK + blk) * CB + tid];
    __syncthreads();
#pragma unroll
    for (int e = 0; e < EPT; e++) {
        int i = base + e * 256 + tid;
        int2 en;
        en.x = src[i] | (cat[i] << 18);
        en.y = dd[e];
        cbuf[(size_t)t * E_EDGES + gbase[bb[e]] + rank[e]] = en;
    }
}

__global__ __launch_bounds__(256) void fine_build(
    const int2* __restrict__ cbuf, const int* __restrict__ coffs,
    int4* __restrict__ meta, int* __restrict__ sorted) {
    int t = blockIdx.x >> 6;
    int b = blockIdx.x & 63;
    int node0 = b * BSPAN;
    int nodes = min(BSPAN, N_NODES - node0);
    int ebeg = coffs[t * (CB + 1) + b];
    int eend = coffs[t * (CB + 1) + b + 1];
    const int2* ebuf = cbuf + (size_t)t * E_EDGES;
    int4* mt = meta + (size_t)t * NODE_STRIDE;
    int* srt = sorted + (size_t)t * E_EDGES;
    __shared__ int cnt[BSPAN];     // counts -> cursor
    __shared__ int begs[BSPAN];    // local exclusive offsets
    __shared__ int sums[256];
    int tid = threadIdx.x;

    for (int j = tid; j < BSPAN; j += 256) cnt[j] = 0;
    __syncthreads();
    for (int e = ebeg + tid; e < eend; e += 256)
        atomicAdd(&cnt[ebuf[e].y - node0], 1);
    __syncthreads();

    const int chunk = (BSPAN + 255) / 256;   // 10
    int cbeg = tid * chunk;
    int cend = min(cbeg + chunk, BSPAN);
    int s = 0;
    for (int j = cbeg; j < cend; j++) s += cnt[j];
    sums[tid] = s;
    __syncthreads();
    for (int d = 1; d < 256; d <<= 1) {
        int v = (tid >= d) ? sums[tid - d] : 0;
        __syncthreads();
        sums[tid] += v;
        __syncthreads();
    }
    int run = (tid == 0) ? 0 : sums[tid - 1];
    for (int j = cbeg; j < cend; j++) {
        int c = cnt[j];
        begs[j] = run;
        cnt[j] = run;                // cursor
        run += c;
    }
    __syncthreads();

    for (int e = ebeg + tid; e < eend; e += 256) {
        int2 en = ebuf[e];
        int pos = atomicAdd(&cnt[en.y - node0], 1);
        srt[ebeg + pos] = en.x;
    }
    __syncthreads();

    for (int j = tid; j < nodes; j += 256) {
        int lbeg = begs[j];
        int deg = cnt[j] - lbeg;
        int gbeg = ebeg + lbeg;
        int4 m;
        m.x = gbeg | (deg << 19);    // gbeg <= 2^18, deg < 2^13
        m.y = (deg > 0) ? srt[gbeg] : 0;
        m.z = (deg > 1) ? srt[gbeg + 1] : 0;
        m.w = (deg > 2) ? srt[gbeg + 2] : 0;
        mt[node0 + j] = m;
    }
}

// ============ Per-step fused aggregation + residual (gather, no atomics) ====
// emb_out[n] = emb_in[n] + mean_{e in bucket(n)} emb_in[src_e] * rel[cat_e]
__global__ __launch_bounds__(256) void fused_agg(
    const float* __restrict__ emb_in, float* __restrict__ emb_out,
    const float* __restrict__ rel_emb, const int4* __restrict__ meta,
    const int* __restrict__ sorted) {
    int g = threadIdx.x >> 5;
    int lane = threadIdx.x & 31;
    int node = blockIdx.x * NPB + g;
    if (node >= N_NODES) return;
    bool act = lane < D4;
    float4 own = act ? ((const float4*)(emb_in + (size_t)node * DIM))[lane]
                     : make_float4(0.f, 0.f, 0.f, 0.f);
    int4 m = meta[node];                 // broadcast: beg|deg, p0, p1, p2
    int deg = ((unsigned)m.x) >> 19;
    int beg = m.x & 0x7FFFF;
    float4 acc = make_float4(0.f, 0.f, 0.f, 0.f);
    if (act) {
        if (deg > 0) {
            float4 mm = ((const float4*)(emb_in + (size_t)(m.y & 0x3FFFF) * DIM))[lane];
            float4 rr = ((const float4*)(rel_emb + (size_t)(m.y >> 18) * DIM))[lane];
            acc.x += mm.x * rr.x; acc.y += mm.y * rr.y;
            acc.z += mm.z * rr.z; acc.w += mm.w * rr.w;
        }
        if (deg > 1) {
            float4 mm = ((const float4*)(emb_in + (size_t)(m.z & 0x3FFFF) * DIM))[lane];
            float4 rr = ((const float4*)(rel_emb + (size_t)(m.z >> 18) * DIM))[lane];
            acc.x += mm.x * rr.x; acc.y += mm.y * rr.y;
            acc.z += mm.z * rr.z; acc.w += mm.w * rr.w;
        }
        if (deg > 2) {
            float4 mm = ((const float4*)(emb_in + (size_t)(m.w & 0x3FFFF) * DIM))[lane];
            float4 rr = ((const float4*)(rel_emb + (size_t)(m.w >> 18) * DIM))[lane];
            acc.x += mm.x * rr.x; acc.y += mm.y * rr.y;
            acc.z += mm.z * rr.z; acc.w += mm.w * rr.w;
        }
    }
    // overflow path (deg > 3): walk CSR slice
    for (int e = beg + 3; e < beg + deg; e++) {
        int p = sorted[e];
        if (act) {
            float4 mm = ((const float4*)(emb_in + (size_t)(p & 0x3FFFF) * DIM))[lane];
            float4 rr = ((const float4*)(rel_emb + (size_t)(p >> 18) * DIM))[lane];
            acc.x += mm.x * rr.x; acc.y += mm.y * rr.y;
            acc.z += mm.z * rr.z; acc.w += mm.w * rr.w;
        }
    }
    if (act) {
        float inv = (deg > 0) ? 1.0f / (float)deg : 0.0f;
        own.x += acc.x * inv; own.y += acc.y * inv;
        own.z += acc.z * inv; own.w += acc.w * inv;
        ((float4*)(emb_out + (size_t)node * DIM))[lane] = own;
    }
}

// ============ LSTM on seeds (x from emb_new, h_prev from emb_old) ===========
__global__ __launch_bounds__(512) void lstm_kernel(
    const float* __restrict__ emb_new, const float* __restrict__ emb_old,
    const float* __restrict__ c_state, const int* __restrict__ seeds,
    const float* __restrict__ W_ih, const float* __restrict__ W_hh,
    const float* __restrict__ b_ih, const float* __restrict__ b_hh,
    float* __restrict__ h_out, float* __restrict__ c_out) {
    __shared__ __align__(16) float xs[SPB][DIM];
    __shared__ __align__(16) float hs[SPB][DIM];
    __shared__ __align__(16) float gates[SPB][4 * DIM];
    int tid = threadIdx.x;
    int base = blockIdx.x * SPB;

    // float4-vectorized staging (identical values, wider loads)
    for (int idx = tid; idx < SPB * D4; idx += 512) {
        int s = idx / D4, q = idx - s * D4;
        int node = seeds[base + s];
        ((float4*)xs[s])[q] = ((const float4*)(emb_new + (size_t)node * DIM))[q];
        ((float4*)hs[s])[q] = ((const float4*)(emb_old + (size_t)node * DIM))[q];
    }
    __syncthreads();

    if (tid < 4 * DIM) {
        int j = tid;
        float acc[SPB];
#pragma unroll
        for (int s = 0; s < SPB; s++) acc[s] = 0.0f;
        const float4* wi = (const float4*)(W_ih + (size_t)j * DIM);
        const float4* wh = (const float4*)(W_hh + (size_t)j * DIM);
        for (int dc = 0; dc < D4; dc++) {
            float4 a = wi[dc], b = wh[dc];
#pragma unroll
            for (int s = 0; s < SPB; s++) {
                float4 x = ((const float4*)xs[s])[dc];
                float4 h = ((const float4*)hs[s])[dc];
                acc[s] += x.x * a.x + x.y * a.y + x.z * a.z + x.w * a.w
                        + h.x * b.x + h.y * b.y + h.z * b.z + h.w * b.w;
            }
        }
        float bb = b_ih[j] + b_hh[j];
#pragma unroll
        for (int s = 0; s < SPB; s++) gates[s][j] = acc[s] + bb;
    }
    __syncthreads();

    // float4-vectorized activation tail (same per-element math)
    for (int idx = tid; idx < SPB * D4; idx += 512) {
        int s = idx / D4, q = idx - s * D4;
        int node = seeds[base + s];
        float4 ig = ((const float4*)gates[s])[q];
        float4 fg = ((const float4*)(gates[s] + DIM))[q];
        float4 gg = ((const float4*)(gates[s] + 2 * DIM))[q];
        float4 og = ((const float4*)(gates[s] + 3 * DIM))[q];
        float4 cp = ((const float4*)(c_state + (size_t)node * DIM))[q];
        float4 cn, hn;
        cn.x = sigmoidf_(fg.x) * cp.x + sigmoidf_(ig.x) * tanhf(gg.x);
        cn.y = sigmoidf_(fg.y) * cp.y + sigmoidf_(ig.y) * tanhf(gg.y);
        cn.z = sigmoidf_(fg.z) * cp.z + sigmoidf_(ig.z) * tanhf(gg.z);
        cn.w = sigmoidf_(fg.w) * cp.w + sigmoidf_(ig.w) * tanhf(gg.w);
        hn.x = sigmoidf_(og.x) * tanhf(cn.x);
        hn.y = sigmoidf_(og.y) * tanhf(cn.y);
        hn.z = sigmoidf_(og.z) * tanhf(cn.z);
        hn.w = sigmoidf_(og.w) * tanhf(cn.w);
        ((float4*)(h_out + (size_t)(base + s) * DIM))[q] = hn;
        ((float4*)(c_out + (size_t)(base + s) * DIM))[q] = cn;
    }
}

// duplicate seeds write identical values -> benign
__global__ __launch_bounds__(256) void scatter_seed(
    float* __restrict__ emb, float* __restrict__ c_state,
    const int* __restrict__ seeds,
    const float* __restrict__ h_new, const float* __restrict__ c_new) {
    int i = blockIdx.x * blockDim.x + threadIdx.x;  // over S*D4
    int sd = i / D4, q = i - sd * D4;
    int node = seeds[sd];
    ((float4*)(emb + (size_t)node * DIM))[q] =
        ((const float4*)(h_new + (size_t)sd * DIM))[q];
    ((float4*)(c_state + (size_t)node * DIM))[q] =
        ((const float4*)(c_new + (size_t)sd * DIM))[q];
}

// ============ Scoring ============
__global__ __launch_bounds__(64) void score_kernel(
    const float* __restrict__ seed_h, const float* __restrict__ emb,
    const int* __restrict__ cand_idx, float* __restrict__ out) {
    int n = blockIdx.x;
    int lane = threadIdx.x;
    float u0 = seed_h[(size_t)n * DIM + lane];
    float u1 = (lane + 64 < DIM) ? seed_h[(size_t)n * DIM + lane + 64] : 0.0f;
    for (int k = 0; k < K_CAND; k++) {
        int node = cand_idx[n * K_CAND + k];
        const float* ce = emb + (size_t)node * DIM;
        float p = u0 * ce[lane];
        if (lane + 64 < DIM) p += u1 * ce[lane + 64];
        for (int off = 32; off > 0; off >>= 1) p += __shfl_down(p, off);
        if (lane == 0) out[n * K_CAND + k] = p;
    }
}

extern "C" void kernel_launch(void* const* d_in, const int* in_sizes, int n_in,
                              void* d_out, int out_size, void* d_ws, size_t ws_size,
                              hipStream_t stream) {
    const float* node_emb = (const float*)d_in[0];
    const float* cx       = (const float*)d_in[1];
    const float* rel_emb  = (const float*)d_in[2];
    const float* W_ih     = (const float*)d_in[3];
    const float* W_hh     = (const float*)d_in[4];
    const float* b_ih     = (const float*)d_in[5];
    const float* b_hh     = (const float*)d_in[6];
    const int*   src      = (const int*)d_in[7];
    const int*   dst      = (const int*)d_in[8];
    const int*   cat      = (const int*)d_in[9];
    const int*   seeds    = (const int*)d_in[10];
    const int*   cand     = (const int*)d_in[11];
    float* out = (float*)d_out;

    char* wsb = (char*)d_ws;
    float* emb_a = (float*)wsb; wsb += sizeof(float) * (size_t)N_NODES * DIM;
    float* emb_b = (float*)wsb; wsb += sizeof(float) * (size_t)N_NODES * DIM;
    float* cst   = (float*)wsb; wsb += sizeof(float) * (size_t)N_NODES * DIM;
    float* cnew  = (float*)wsb; wsb += sizeof(float) * (size_t)S_SEEDS * DIM;
    float* seedh = (float*)wsb; wsb += sizeof(float) * (size_t)T_STEPS * S_SEEDS * DIM;
    int4* meta   = (int4*)wsb; wsb += sizeof(int4) * (size_t)T_STEPS * NODE_STRIDE;
    int* sorted  = (int*)wsb; wsb += sizeof(int) * (size_t)T_STEPS * E_EDGES;
    int* bh      = (int*)wsb; wsb += sizeof(int) * (size_t)T_STEPS * CBLK * CB;
    int* coffs   = (int*)wsb; wsb += sizeof(int) * T_STEPS * (CB + 1);
    // coarse entry buffer (33.6 MB) aliases emb_b: dead until first fused_agg
    int2* cbuf = (int2*)emb_b;

    // ---- CSR build for all 16 steps (atomic-free two-level sort) ----
    coarse_hist<<<T_STEPS * CBLK, 256, 0, stream>>>(dst, bh);
    scan_bh<<<T_STEPS, 64, 0, stream>>>(bh, coffs);
    coarse_scatter<<<T_STEPS * CBLK, 256, 0, stream>>>(
        src, dst, cat, bh, coffs, cbuf);
    fine_build<<<T_STEPS * CB, 256, 0, stream>>>(cbuf, coffs, meta, sorted);

    hipMemcpyAsync(cst, cx, sizeof(float) * (size_t)N_NODES * DIM,
                   hipMemcpyDeviceToDevice, stream);

    const float* cur = node_emb;     // t=0 reads input table directly
    float* bufs[2] = {emb_b, emb_a};
    for (int t = 0; t < T_STEPS; t++) {
        float* nxt = bufs[t & 1];
        fused_agg<<<(N_NODES + NPB - 1) / NPB, 256, 0, stream>>>(
            cur, nxt, rel_emb,
            meta + (size_t)t * NODE_STRIDE, sorted + (size_t)t * E_EDGES);
        lstm_kernel<<<S_SEEDS / SPB, 512, 0, stream>>>(
            nxt, cur, cst, seeds + (size_t)t * S_SEEDS,
            W_ih, W_hh, b_ih, b_hh,
            seedh + (size_t)t * S_SEEDS * DIM, cnew);
        scatter_seed<<<(S_SEEDS * D4) / 256, 256, 0, stream>>>(
            nxt, cst, seeds + (size_t)t * S_SEEDS,
            seedh + (size_t)t * S_SEEDS * DIM, cnew);
        cur = nxt;
    }
    score_kernel<<<T_STEPS * S_SEEDS, 64, 0, stream>>>(seedh, cur, cand, out);
}